// Round 10
// baseline (3178.616 us; speedup 1.0000x reference)
//
#include <hip/hip_runtime.h>
#include <cstddef>
#include <cstdint>

// 2-layer LSTM decoder, B=2048, Z=64, H=256, D=8, T=250. fp32 in/out.
//
// R10 = R9 (3.06 ms, i8 hi/lo + 4-slot LDS ring, no spills) with the serial
// barrier structure thinned 5 -> 3 per step:
//  - h0 region of X double-buffered by step parity (pb0/pb1): cell0 writes
//    the opposite buffer from L0 readers -> barrier (a) removed.
//  - x-load moved to step end (loads target[:,t] for step t+1; x_lds
//    zeroed once) -> barrier (1) removed + t==0 branch gone; x latency
//    hides under cell1.
//  - h1f dropped (pays for the +8 KB h0 double buffer); out-proj reads the
//    i8 hi/lo planes directly (R8-verified, absmax 1.95e-3).
// Barriers left: (b) h0' visibility, (c) L1-read WAR vs cell1 h1-write,
// (d) h1/x visibility before outproj/next step. LDS 60.6 KB.

#define BSZ    2048
#define ZDIM   64
#define HDIM   256
#define DDIM   8
#define TSTEPS 250
#define ROWS   16
#define NWG    (BSZ / ROWS)   // 128
#define NTH    512            // 8 waves
#define G4     1024
#define WSTR   264            // woutT row stride (shorts)

typedef __attribute__((ext_vector_type(4))) int v4i;

__device__ __forceinline__ unsigned short f2bf(float x) {   // RNE f32->bf16
  union { float f; unsigned u; } v; v.f = x;
  unsigned r = v.u + 0x7fff + ((v.u >> 16) & 1);
  return (unsigned short)(r >> 16);
}
__device__ __forceinline__ float bf2f(unsigned short b) {
  union { unsigned u; float f; } v; v.u = (unsigned)b << 16; return v.f;
}
__device__ __forceinline__ float fexp2(float x) { return __builtin_amdgcn_exp2f(x); }
__device__ __forceinline__ float frcp(float x)  { return __builtin_amdgcn_rcpf(x); }
__device__ __forceinline__ float sigm(float x)  { return frcp(1.f + fexp2(-1.44269504f * x)); }
__device__ __forceinline__ float tanh_(float x) { return 2.f * frcp(1.f + fexp2(-2.88539008f * x)) - 1.f; }
__device__ __forceinline__ char q8(float x, float s) {
  float v = fminf(fmaxf(x * s, -127.f), 127.f);
  return (char)(int)__builtin_rintf(v);
}
// h*s split into hi + lo/254 (lo in [-127,127] exactly since 0.5*254=127)
__device__ __forceinline__ void q8pair(float h, float s, char* hi, char* lo) {
  float hs = fminf(fmaxf(h * s, -127.f), 127.f);
  float hq = __builtin_rintf(hs);
  *hi = (char)(int)hq;
  *lo = (char)(int)__builtin_rintf((hs - hq) * 254.f);
}

// async 16B/lane global->LDS DMA (verified R3/R7-R9)
__device__ __forceinline__ void async_copy16(const void* g, void* l) {
  __builtin_amdgcn_global_load_lds(
      reinterpret_cast<const __attribute__((address_space(1))) unsigned int*>(
          reinterpret_cast<uintptr_t>(g)),
      reinterpret_cast<__attribute__((address_space(3))) unsigned int*>(
          reinterpret_cast<uintptr_t>(l)),
      16, 0, 0);
}
template <int N>
__device__ __forceinline__ void wait_vmcnt() {
  __builtin_amdgcn_s_waitcnt((N & 15) | (7 << 4) | (15 << 8) | (((N >> 4) & 3) << 14));
}

// ---------------- initial state (mapping verified R1-R9) ----------------
__global__ void init_state(const float* __restrict__ z,
                           const float* __restrict__ Wfh, const float* __restrict__ bfh,
                           const float* __restrict__ Wfc, const float* __restrict__ bfc,
                           char* __restrict__ h0h, char* __restrict__ h0l,
                           char* __restrict__ h1h, char* __restrict__ h1l,
                           float* __restrict__ c0s, float* __restrict__ c1s)
{
  int idx = blockIdx.x * 256 + threadIdx.x;
  int b = idx >> 8;
  int j = idx & 255;
  int col = ((b & 1) << 8) | j;
  const float* z0 = z + (size_t)(b >> 1) * ZDIM;
  const float* z1 = z + (size_t)(1024 + (b >> 1)) * ZDIM;
  float h0 = bfh[col], c0v = bfc[col], h1 = bfh[col], c1v = bfc[col];
  for (int k = 0; k < ZDIM; ++k) {
    float wh = Wfh[k * 512 + col];
    float wc = Wfc[k * 512 + col];
    float a = z0[k], bb = z1[k];
    h0  += a * wh;  c0v += a * wc;
    h1  += bb * wh; c1v += bb * wc;
  }
  char hi, lo;
  q8pair(h0, 31.75f, &hi, &lo); h0h[idx] = hi; h0l[idx] = lo;
  q8pair(h1, 31.75f, &hi, &lo); h1h[idx] = hi; h1l[idx] = lo;
  c0s[idx] = c0v; c1s[idx] = c1v;
}

// ---------------- per-output-column scales (unchanged) ----------------
__global__ void col_scales(const float* __restrict__ Whh0,
                           const float* __restrict__ Wih1, const float* __restrict__ Whh1,
                           float* __restrict__ cs0, float* __restrict__ qs0,
                           float* __restrict__ cs1, float* __restrict__ qs1)
{
  int c = blockIdx.x * 256 + threadIdx.x;   // 0..2047
  if (c < 1024) {
    float m = 0.f;
    for (int k = 0; k < 256; ++k) m = fmaxf(m, fabsf(Whh0[(size_t)k * G4 + c]));
    cs0[c] = m * (1.f / 16129.f);
    qs0[c] = 127.f / m;
  } else {
    c -= 1024;
    float m = 0.f;
    for (int k = 0; k < 256; ++k) m = fmaxf(m, fabsf(Whh1[(size_t)k * G4 + c]));
    for (int k = 0; k < 256; ++k) m = fmaxf(m, fabsf(Wih1[(size_t)k * G4 + c]));
    cs1[c] = m * (1.f / 16129.f);
    qs1[c] = 127.f / m;
  }
}

// ---- i8 weight pack: per-wave-contiguous linear stream (verified R8/R9) ----
__global__ void pack_i8(const float* __restrict__ Whh0,
                        const float* __restrict__ Wih1, const float* __restrict__ Whh1,
                        const float* __restrict__ qs0, const float* __restrict__ qs1,
                        char* __restrict__ p0, char* __restrict__ p1)
{
  int tt   = blockIdx.x * 4 + (threadIdx.x >> 6);   // 0..767
  int lane = threadIdx.x & 63;
  int l15 = lane & 15, lq = lane >> 4;
  union { char c[16]; uint4 u; } v;
  if (tt < 256) {                                   // layer0: w*4+kc, i
    int w = tt >> 5, kc = (tt >> 3) & 3, i = tt & 7;
    int nt = (i >> 1) * 16 + 2 * w + (i & 1);
    int col = nt * 16 + l15;
    float q = qs0[col];
    for (int j = 0; j < 16; ++j) {
      int k = kc * 64 + lq * 16 + j;
      v.c[j] = q8(Whh0[(size_t)k * G4 + col], q);
    }
    *(uint4*)(p0 + (size_t)tt * 1024 + lane * 16) = v.u;
  } else {                                          // layer1: w*8+kc, i
    int t1 = tt - 256;
    int w = t1 >> 6, kc = (t1 >> 3) & 7, i = t1 & 7;
    int nt = (i >> 1) * 16 + 2 * w + (i & 1);
    int col = nt * 16 + l15;
    float q = qs1[col];
    for (int j = 0; j < 16; ++j) {
      int k = kc * 64 + lq * 16 + j;
      float wv = (k < 256) ? Whh1[(size_t)k * G4 + col]
                           : Wih1[(size_t)(k - 256) * G4 + col];
      v.c[j] = q8(wv, q);
    }
    *(uint4*)(p1 + (size_t)t1 * 1024 + lane * 16) = v.u;
  }
}

// ---------------- persistent LSTM kernel ----------------
__global__ __launch_bounds__(NTH, 1) void lstm_run(
    const float* __restrict__ target,
    const char* __restrict__ p0, const char* __restrict__ p1,
    const float* __restrict__ bih0, const float* __restrict__ bhh0,
    const float* __restrict__ bih1, const float* __restrict__ bhh1,
    const float* __restrict__ Wih0,            // [8,1024] fp32 -> 64 VGPRs/thread
    const float* __restrict__ Wout, const float* __restrict__ bout,
    const char* __restrict__ h0h, const char* __restrict__ h0l,
    const char* __restrict__ h1h, const char* __restrict__ h1l,
    const float* __restrict__ c0s, const float* __restrict__ c1s,
    const float* __restrict__ cs0, const float* __restrict__ cs1,
    float* __restrict__ out)
{
  // X planes, 48 blocks of (16 rows x 16 K-bytes):
  //   blks 0..15  : h1 (single buffer)
  //   blks 16..31 : h0 buffer 0   (pb = 16)
  //   blks 32..47 : h0 buffer 1   (pb = 32)
  __shared__ uint4 ring[8][4][64];                 // 32 KB: per-wave 4x1KB slots
  __shared__ uint4 X4h[48 * 16];                   // 12 KB
  __shared__ uint4 X4l[48 * 16];                   // 12 KB
  __shared__ unsigned short woutT[8 * WSTR];       // 4.1 KB bf16
  __shared__ float x_lds[16 * 8];                  // 0.5 KB  (total ~60.6 KB)

  const int tid  = threadIdx.x;
  const int w    = tid >> 6;
  const int lane = tid & 63;
  const int l15  = lane & 15;
  const int lq   = lane >> 4;
  const int b0   = blockIdx.x * ROWS;
  char* Xch = (char*)X4h;
  char* Xcl = (char*)X4l;

  // ---- one-time staging: h1 -> blks 0..15, h0 -> blks 16..31 (buf 0) ----
  {
    int m = tid & 15, blk = tid >> 4;              // 32 blks x 16 m
    const char* sh = (blk < 16) ? h1h : h0h;
    const char* sl = (blk < 16) ? h1l : h0l;
    int jblk = blk & 15;
    X4h[blk * 16 + m] = *(const uint4*)(sh + (size_t)(b0 + m) * HDIM + jblk * 16);
    X4l[blk * 16 + m] = *(const uint4*)(sl + (size_t)(b0 + m) * HDIM + jblk * 16);
  }
  for (int i = tid; i < HDIM * DDIM; i += NTH) {
    int k = i >> 3, d = i & 7;
    woutT[d * WSTR + k] = f2bf(Wout[i]);
  }
  if (tid < 128) x_lds[tid] = 0.f;                 // x(0) = 0

  const int myrow = lq * 4;
  const int jc0   = 32 * w + l15;
  float c0r[2][4], c1r[2][4];
  float bA0[8], bA1[8], csA0[8], csA1[8];          // flat [g*2+cc]
  float wx[8][8];                                  // Wih0[d][col(i)] in regs
#pragma unroll
  for (int i = 0; i < 8; ++i) {
    int col = (i >> 1) * 256 + jc0 + 16 * (i & 1);
    bA0[i]  = bih0[col] + bhh0[col];
    bA1[i]  = bih1[col] + bhh1[col];
    csA0[i] = cs0[col];
    csA1[i] = cs1[col];
#pragma unroll
    for (int d = 0; d < 8; ++d) wx[i][d] = Wih0[d * G4 + col];
  }
#pragma unroll
  for (int cc = 0; cc < 2; ++cc) {
    int j = jc0 + cc * 16;
#pragma unroll
    for (int r = 0; r < 4; ++r) {
      c0r[cc][r] = c0s[(size_t)(b0 + myrow + r) * HDIM + j];
      c1r[cc][r] = c1s[(size_t)(b0 + myrow + r) * HDIM + j];
    }
  }
  const int opr = tid >> 5, opd = (tid >> 2) & 7, opq = tid & 3;
  const float bo_out = bout[opd];

  // per-lane weight stream bases; tile j at base + j*1024 (linear)
  const char* gp0 = p0 + (size_t)w * 32768 + lane * 16;
  const char* gp1 = p1 + (size_t)w * 65536 + lane * 16;

  // A-frag reads: pb0 = this step's h0 source buffer, pb1 = h0' dest buffer
#define A0VH(KC) __builtin_bit_cast(v4i, X4h[(pb0 + (KC) * 4 + lq) * 16 + l15])
#define A0VL(KC) __builtin_bit_cast(v4i, X4l[(pb0 + (KC) * 4 + lq) * 16 + l15])
#define A1VH(KC) __builtin_bit_cast(v4i, \
    X4h[(((KC) < 4 ? (KC) * 4 : pb1 + ((KC) - 4) * 4) + lq) * 16 + l15])
#define A1VL(KC) __builtin_bit_cast(v4i, \
    X4l[(((KC) < 4 ? (KC) * 4 : pb1 + ((KC) - 4) * 4) + lq) * 16 + l15])

  // initial prologue: L0 tiles 0..3 -> slots 0..3
  async_copy16(gp0,        &ring[w][0][0]);
  async_copy16(gp0 + 1024, &ring[w][1][0]);
  async_copy16(gp0 + 2048, &ring[w][2][0]);
  async_copy16(gp0 + 3072, &ring[w][3][0]);

  __syncthreads();

#pragma unroll 1
  for (int t = 0; t < TSTEPS; ++t) {
    const int pb0 = 16 + ((t & 1) << 4);           // h0 source (h0'(t-1))
    const int pb1 = 48 - pb0;                      // h0' dest (read by L1(t), L0(t+1))
    const float sc0 = (t <= 1) ? 4.f : 1.f;
    const float sc1 = (t == 0) ? 4.f : 1.f;
    const float wq0 = (t == 0) ? 31.75f : 127.f;

    v4i acch[8], accl[8];
    const v4i zi = {0, 0, 0, 0};

    // ============ layer 0: h0 @ Whh0 (32 tiles, slot = j&3) ============
#pragma unroll
    for (int i = 0; i < 8; ++i) { acch[i] = zi; accl[i] = zi; }
    {
      v4i ah, al;
#pragma unroll 8
      for (int j = 0; j < 32; ++j) {
        const int i = j & 7, s = j & 3;
        if (i == 0) { int kc = j >> 3; ah = A0VH(kc); al = A0VL(kc); }
        wait_vmcnt<3>();
        v4i bb = __builtin_bit_cast(v4i, ring[w][s][lane]);
        acch[i] = __builtin_amdgcn_mfma_i32_16x16x64_i8(ah, bb, acch[i], 0, 0, 0);
        accl[i] = __builtin_amdgcn_mfma_i32_16x16x64_i8(al, bb, accl[i], 0, 0, 0);
        const int jn = j + 4;
        if (jn < 32) async_copy16(gp0 + (size_t)jn * 1024, &ring[w][s][0]);
        else         async_copy16(gp1 + (size_t)(jn - 32) * 1024, &ring[w][s][0]);
      }
    }
    // NO barrier: cell0 writes h0' into buffer pb1, L0 readers used pb0.

    // ---- cell 0: dequant + fp32 x-path from registers ----
    {
      float4 xa[4], xb[4];
#pragma unroll
      for (int r = 0; r < 4; ++r) {
        xa[r] = *(const float4*)&x_lds[(myrow + r) * 8];
        xb[r] = *(const float4*)&x_lds[(myrow + r) * 8 + 4];
      }
#pragma unroll
      for (int cc = 0; cc < 2; ++cc) {
        float gf4[4][4];
#pragma unroll
        for (int g = 0; g < 4; ++g) {
          int i = g * 2 + cc;
          float cs = csA0[i] * sc0;
#pragma unroll
          for (int r = 0; r < 4; ++r)
            gf4[g][r] = ((float)acch[i][r] + (float)accl[i][r] * (1.f / 254.f)) * cs + bA0[i];
        }
#pragma unroll
        for (int g = 0; g < 4; ++g) {
          int i = g * 2 + cc;
#pragma unroll
          for (int r = 0; r < 4; ++r)
            gf4[g][r] += xa[r].x * wx[i][0] + xa[r].y * wx[i][1]
                       + xa[r].z * wx[i][2] + xa[r].w * wx[i][3]
                       + xb[r].x * wx[i][4] + xb[r].y * wx[i][5]
                       + xb[r].z * wx[i][6] + xb[r].w * wx[i][7];
        }
#pragma unroll
        for (int r = 0; r < 4; ++r) {
          float iv = sigm(gf4[0][r]);
          float fv = sigm(gf4[1][r]);
          float gv = tanh_(gf4[2][r]);
          float ov = sigm(gf4[3][r]);
          c0r[cc][r] = fv * c0r[cc][r] + iv * gv;
          char hi, lo;
          q8pair(ov * tanh_(c0r[cc][r]), wq0, &hi, &lo);
          int off = ((pb1 + 2 * w + cc) * 16 + myrow + r) * 16 + l15;
          Xch[off] = hi; Xcl[off] = lo;
        }
      }
    }
    __syncthreads();   // (b) h0' visible to all waves

    // ============ layer 1: [h1|h0'] @ W1 (64 tiles, slot = j&3) ============
#pragma unroll
    for (int i = 0; i < 8; ++i) { acch[i] = zi; accl[i] = zi; }
    {
      v4i ah, al;
#pragma unroll 8
      for (int j = 0; j < 64; ++j) {
        const int i = j & 7, s = j & 3;
        if (i == 0) { int kc = j >> 3; ah = A1VH(kc); al = A1VL(kc); }
        wait_vmcnt<3>();
        v4i bb = __builtin_bit_cast(v4i, ring[w][s][lane]);
        acch[i] = __builtin_amdgcn_mfma_i32_16x16x64_i8(ah, bb, acch[i], 0, 0, 0);
        accl[i] = __builtin_amdgcn_mfma_i32_16x16x64_i8(al, bb, accl[i], 0, 0, 0);
        const int jn = j + 4;
        if (jn < 64) async_copy16(gp1 + (size_t)jn * 1024, &ring[w][s][0]);
        else         async_copy16(gp0 + (size_t)(jn - 64) * 1024, &ring[w][s][0]);
      }
    }
    __syncthreads();   // (c) all waves' L1 A-reads done; h1 may be overwritten

    // ---- cell 1: dequant + activations + h1 i8 stores ----
#pragma unroll
    for (int cc = 0; cc < 2; ++cc)
#pragma unroll
      for (int r = 0; r < 4; ++r) {
        float di = ((float)acch[0 + cc][r] + (float)accl[0 + cc][r] * (1.f / 254.f));
        float df = ((float)acch[2 + cc][r] + (float)accl[2 + cc][r] * (1.f / 254.f));
        float dg = ((float)acch[4 + cc][r] + (float)accl[4 + cc][r] * (1.f / 254.f));
        float dv = ((float)acch[6 + cc][r] + (float)accl[6 + cc][r] * (1.f / 254.f));
        float iv = sigm(di * csA1[0 + cc] * sc1 + bA1[0 + cc]);
        float fv = sigm(df * csA1[2 + cc] * sc1 + bA1[2 + cc]);
        float gv = tanh_(dg * csA1[4 + cc] * sc1 + bA1[4 + cc]);
        float ov = sigm(dv * csA1[6 + cc] * sc1 + bA1[6 + cc]);
        c1r[cc][r] = fv * c1r[cc][r] + iv * gv;
        float h = ov * tanh_(c1r[cc][r]);
        char hi, lo;
        q8pair(h, 127.f, &hi, &lo);
        int off = ((2 * w + cc) * 16 + myrow + r) * 16 + l15;
        Xch[off] = hi; Xcl[off] = lo;
      }

    // ---- load x(t+1) = target[:, t] (implicit vmcnt drain hits aged tiles) ----
    if (tid < 128) {
      int m = tid >> 3, d = tid & 7;
      x_lds[m * 8 + d] =
          target[(size_t)(b0 + m) * (TSTEPS * DDIM) + (size_t)t * DDIM + d];
    }
    __syncthreads();   // (d) h1 + x(t+1) visible

    // ---- out projection from i8 hi/lo planes + shfl reduce over opq ----
    {
      float s_ = 0.f;
#pragma unroll
      for (int i = 0; i < 16; ++i) {
        int off = (i * 16 + opr) * 16 + opq * 4;
        int hb = *(const int*)(Xch + off);
        int lb = *(const int*)(Xcl + off);
        ushort4 wv = *(const ushort4*)&woutT[opd * WSTR + i * 16 + opq * 4];
        const unsigned short* wp = (const unsigned short*)&wv;
#pragma unroll
        for (int q = 0; q < 4; ++q) {
          float hv = (float)((char)(hb >> (8 * q)))
                   + (float)((char)(lb >> (8 * q))) * (1.f / 254.f);
          s_ += hv * bf2f(wp[q]);
        }
      }
      s_ += __shfl_xor(s_, 1);
      s_ += __shfl_xor(s_, 2);
      if (opq == 0)
        out[(size_t)(b0 + opr) * (TSTEPS * DDIM) + (size_t)t * DDIM + opd] =
            s_ * (1.f / 127.f) + bo_out;
    }
    // no barrier: next L0 touches only h0buf[pb] and ring (own slots);
    // first h1-writer is cell1(t+1), fenced by barriers (b),(c) of t+1.
  }
#undef A0VH
#undef A0VL
#undef A1VH
#undef A1VL
}

extern "C" void kernel_launch(void* const* d_in, const int* in_sizes, int n_in,
                              void* d_out, int out_size, void* d_ws, size_t ws_size,
                              hipStream_t stream) {
  const float* z    = (const float*)d_in[0];
  const float* tgt  = (const float*)d_in[1];
  const float* Wfh  = (const float*)d_in[2];
  const float* bfh  = (const float*)d_in[3];
  const float* Wfc  = (const float*)d_in[4];
  const float* bfc  = (const float*)d_in[5];
  const float* Wih0 = (const float*)d_in[6];
  const float* Whh0 = (const float*)d_in[7];
  const float* bih0 = (const float*)d_in[8];
  const float* bhh0 = (const float*)d_in[9];
  const float* Wih1 = (const float*)d_in[10];
  const float* Whh1 = (const float*)d_in[11];
  const float* bih1 = (const float*)d_in[12];
  const float* bhh1 = (const float*)d_in[13];
  const float* Wout = (const float*)d_in[14];
  const float* bout = (const float*)d_in[15];

  // ws layout (bytes), total ~7.09 MB
  char* ws = (char*)d_ws;
  char*  p0   = ws;                                  // 262,144
  char*  p1   = ws + 262144;                         // 524,288
  char*  h0h  = ws + 786432;                         // 524,288
  char*  h0l  = ws + 1310720;                        // 524,288
  char*  h1h  = ws + 1835008;                        // 524,288
  char*  h1l  = ws + 2359296;                        // 524,288
  float* c0s  = (float*)(ws + 2883584);              // 2,097,152
  float* c1s  = (float*)(ws + 4980736);              // 2,097,152
  float* cs0  = (float*)(ws + 7077888);              // 4,096
  float* qs0  = (float*)(ws + 7081984);              // 4,096
  float* cs1  = (float*)(ws + 7086080);              // 4,096
  float* qs1  = (float*)(ws + 7090176);              // 4,096

  hipLaunchKernelGGL(init_state, dim3(BSZ * HDIM / 256), dim3(256), 0, stream,
                     z, Wfh, bfh, Wfc, bfc, h0h, h0l, h1h, h1l, c0s, c1s);
  hipLaunchKernelGGL(col_scales, dim3(8), dim3(256), 0, stream,
                     Whh0, Wih1, Whh1, cs0, qs0, cs1, qs1);
  hipLaunchKernelGGL(pack_i8, dim3(192), dim3(256), 0, stream,
                     Whh0, Wih1, Whh1, qs0, qs1, p0, p1);
  hipLaunchKernelGGL(lstm_run, dim3(NWG), dim3(NTH), 0, stream,
                     tgt, p0, p1, bih0, bhh0, bih1, bhh1, Wih0, Wout, bout,
                     h0h, h0l, h1h, h1l, c0s, c1s, cs0, cs1, (float*)d_out);
}